// Round 2
// baseline (436.185 us; speedup 1.0000x reference)
//
#include <hip/hip_runtime.h>
#include <hip/hip_cooperative_groups.h>

namespace cgx = cooperative_groups;

// PCEN: out = (x/(FLOOR+m)^alpha + delta)^(1/root) - delta^(1/root)
// m = EMA over T with s=0.025, m_0 = x_0.
// Shapes: x [B=64, T=4096, C=128] f32, alpha/delta/root [C] f32.
//
// Single cooperative kernel:
//   phase 1: per-(b,chunk,cg) chunk-local EMA end value -> ws   (HBM read of x)
//   grid.sync()
//   phase 2: each thread inline-combines the <=63 previous chunk-end values
//            (2 MiB, L2-hot) into its incoming prefix, then recomputes the
//            EMA over its chunk (x re-read is L3-resident) fused with PCEN.

constexpr int Bn = 64, Tn = 4096, Cn = 128;
constexpr int NC = 64;            // chunks along T
constexpr int Lc = Tn / NC;       // 64 timesteps per chunk
constexpr float SC  = 0.025f;
constexpr float OMS = 1.0f - SC;  // 0.975
constexpr float FLOORV = 1e-6f;

// (1-s)^Lc, compile-time
__host__ __device__ constexpr float chunk_decay() {
    float a = 1.0f;
    for (int i = 0; i < Lc; ++i) a *= OMS;
    return a;
}
constexpr float ACH = chunk_decay();

__device__ __forceinline__ float pcen_elem(float x, float m, float al, float dl,
                                           float oor, float t3) {
    float lg   = log2f(FLOORV + m);
    float inv1 = exp2f(-al * lg);               // 1 / (FLOOR+m)^alpha
    float base = fmaf(x, inv1, dl);             // x/term1 + delta  (>0)
    return exp2f(oor * log2f(base)) - t3;
}

// Thread mapping: gid = b*(NC*32) + chunk*32 + cg  (cg = float4 group of channels)
// Consecutive lanes -> consecutive channels -> coalesced float4 accesses
// (each half-wave reads a contiguous 512B segment).

__global__ __launch_bounds__(256, 2) void k_pcen(
        const float* __restrict__ x,
        const float* __restrict__ alpha,
        const float* __restrict__ delta,
        const float* __restrict__ root,
        float* __restrict__ endv,      // workspace: B*NC*C floats = 2 MiB
        float* __restrict__ out)
{
    cgx::grid_group grid = cgx::this_grid();

    const int gid   = blockIdx.x * 256 + threadIdx.x;
    const int cg    = gid & 31;
    const int chunk = (gid >> 5) & (NC - 1);
    const int b     = gid >> 11;

    const size_t xoff = (size_t)(b * Tn + chunk * Lc) * (Cn / 4) + cg;
    const float4* xp  = (const float4*)x + xoff;

    // ---------------- phase 1: chunk-local EMA end value ----------------
    // t = 0 peeled: chunk 0 starts with m = x_0 (a_0 = 0); others zero-init.
    float4 v = xp[0];
    float4 m;
    if (chunk == 0) {
        m = v;
    } else {
        m.x = SC * v.x; m.y = SC * v.y; m.z = SC * v.z; m.w = SC * v.w;
    }
#pragma unroll 8
    for (int t = 1; t < Lc; ++t) {
        v = xp[(size_t)t * (Cn / 4)];
        m.x = fmaf(OMS, m.x, SC * v.x);
        m.y = fmaf(OMS, m.y, SC * v.y);
        m.z = fmaf(OMS, m.z, SC * v.z);
        m.w = fmaf(OMS, m.w, SC * v.w);
    }
    ((float4*)endv)[(size_t)(b * NC + chunk) * (Cn / 4) + cg] = m;

    __threadfence();          // device-scope release of endv before grid sync
    grid.sync();
    __threadfence();          // device-scope acquire (cross-XCD L2 safety)

    // ------- phase 2a: incoming prefix = sum_{j<chunk} ACH^(chunk-1-j)*e_j ----
    // endv is 2 MiB -> L2/L3-hot. Lanes 0-31 and 32-63 of a wave read the
    // same 512B rows (broadcast + next-chunk), trip counts differ by 1.
    const float4* ep = (const float4*)endv + (size_t)b * NC * (Cn / 4) + cg;
    float4 acc = {0.f, 0.f, 0.f, 0.f};
#pragma unroll 4
    for (int j = 0; j < chunk; ++j) {
        float4 e = ep[(size_t)j * (Cn / 4)];
        acc.x = fmaf(ACH, acc.x, e.x);
        acc.y = fmaf(ACH, acc.y, e.y);
        acc.z = fmaf(ACH, acc.z, e.z);
        acc.w = fmaf(ACH, acc.w, e.w);
    }

    // ------- phase 2b: per-channel params -------
    const int c0 = cg * 4;
    float4 al = *(const float4*)(alpha + c0);
    float4 dl = *(const float4*)(delta + c0);
    float4 rt = *(const float4*)(root + c0);
    al.x = fminf(al.x, 1.f); al.y = fminf(al.y, 1.f); al.z = fminf(al.z, 1.f); al.w = fminf(al.w, 1.f);
    rt.x = fmaxf(rt.x, 1.f); rt.y = fmaxf(rt.y, 1.f); rt.z = fmaxf(rt.z, 1.f); rt.w = fmaxf(rt.w, 1.f);
    float4 oor = {1.f / rt.x, 1.f / rt.y, 1.f / rt.z, 1.f / rt.w};
    float4 t3  = {exp2f(oor.x * log2f(dl.x)), exp2f(oor.y * log2f(dl.y)),
                  exp2f(oor.z * log2f(dl.z)), exp2f(oor.w * log2f(dl.w))};

    // ------- phase 2c: fused EMA + PCEN over the chunk (x now L3-hot) -------
    float4* op = (float4*)out + xoff;

    v = xp[0];
    if (chunk == 0) {
        m = v;
    } else {
        m.x = fmaf(OMS, acc.x, SC * v.x);
        m.y = fmaf(OMS, acc.y, SC * v.y);
        m.z = fmaf(OMS, acc.z, SC * v.z);
        m.w = fmaf(OMS, acc.w, SC * v.w);
    }
    float4 o;
    o.x = pcen_elem(v.x, m.x, al.x, dl.x, oor.x, t3.x);
    o.y = pcen_elem(v.y, m.y, al.y, dl.y, oor.y, t3.y);
    o.z = pcen_elem(v.z, m.z, al.z, dl.z, oor.z, t3.z);
    o.w = pcen_elem(v.w, m.w, al.w, dl.w, oor.w, t3.w);
    op[0] = o;

#pragma unroll 4
    for (int t = 1; t < Lc; ++t) {
        v = xp[(size_t)t * (Cn / 4)];
        m.x = fmaf(OMS, m.x, SC * v.x);
        m.y = fmaf(OMS, m.y, SC * v.y);
        m.z = fmaf(OMS, m.z, SC * v.z);
        m.w = fmaf(OMS, m.w, SC * v.w);
        o.x = pcen_elem(v.x, m.x, al.x, dl.x, oor.x, t3.x);
        o.y = pcen_elem(v.y, m.y, al.y, dl.y, oor.y, t3.y);
        o.z = pcen_elem(v.z, m.z, al.z, dl.z, oor.z, t3.z);
        o.w = pcen_elem(v.w, m.w, al.w, dl.w, oor.w, t3.w);
        op[(size_t)t * (Cn / 4)] = o;
    }
}

extern "C" void kernel_launch(void* const* d_in, const int* in_sizes, int n_in,
                              void* d_out, int out_size, void* d_ws, size_t ws_size,
                              hipStream_t stream) {
    const float* x     = (const float*)d_in[0];
    const float* alpha = (const float*)d_in[1];
    const float* delta = (const float*)d_in[2];
    const float* root  = (const float*)d_in[3];
    float* out = (float*)d_out;
    float* ws  = (float*)d_ws;   // needs B*NC*C*4 = 2 MiB

    const int total = Bn * NC * (Cn / 4);        // 131072 threads, 512 blocks
    void* args[] = {(void*)&x, (void*)&alpha, (void*)&delta, (void*)&root,
                    (void*)&ws, (void*)&out};
    hipLaunchCooperativeKernel((const void*)k_pcen, dim3(total / 256), dim3(256),
                               args, 0, stream);
}

// Round 4
// 274.820 us; speedup vs baseline: 1.5872x; 1.5872x over previous
//
#include <hip/hip_runtime.h>

// PCEN: out = (x/(FLOOR+m)^alpha + delta)^(1/root) - delta^(1/root)
// m = EMA over T with s=0.025, m_0 = x_0.
// Shapes: x [B=64, T=4096, C=128] f32, alpha/delta/root [C] f32.
//
// Two regular (graph-capturable) kernels:
//  k_partial: per-(b,chunk,cg) chunk-local EMA end value -> endv (4 MiB ws)
//  k_final:   per-thread incoming prefix from endv (L2-hot, truncated to the
//             last KWIN=32 chunks since ACH^32 ~ 5e-12), then fused EMA+PCEN.
// NC=128 -> 1024 blocks -> 16 waves/CU (2x the previous pipeline's parallelism).
// Round-2 lesson: cooperative fusion hit the traffic floor (274 MB) but was
// latency-bound at 8 waves/CU + uncapturable launch => 436 us. Reverted.

constexpr int Bn = 64, Tn = 4096, Cn = 128;
constexpr int NC = 128;           // chunks along T
constexpr int Lc = Tn / NC;       // 32 timesteps per chunk
constexpr int KWIN = 32;          // prefix window: ACH^KWIN ~ 5e-12, negligible
constexpr float SC  = 0.025f;
constexpr float OMS = 1.0f - SC;  // 0.975
constexpr float FLOORV = 1e-6f;

// (1-s)^Lc, compile-time
__host__ __device__ constexpr float chunk_decay() {
    float a = 1.0f;
    for (int i = 0; i < Lc; ++i) a *= OMS;
    return a;
}
constexpr float ACH = chunk_decay();   // 0.975^32 ~ 0.4448

// Thread mapping: gid = b*(NC*32) + chunk*32 + cg  (cg = float4 group of channels)
// Consecutive lanes -> consecutive channels -> coalesced float4 accesses
// (each half-wave reads a contiguous 512B segment).

__global__ __launch_bounds__(256) void k_partial(const float* __restrict__ x,
                                                 float* __restrict__ endv) {
    int gid   = blockIdx.x * 256 + threadIdx.x;
    int cg    = gid & 31;
    int chunk = (gid >> 5) & (NC - 1);
    int b     = gid >> 12;

    const float4* xp = (const float4*)x + (size_t)(b * Tn + chunk * Lc) * (Cn / 4) + cg;

    // t = 0 peeled: chunk 0 starts with m = x_0 (a_0 = 0); others zero-init.
    float4 v = xp[0];
    float4 m;
    if (chunk == 0) {
        m = v;
    } else {
        m.x = SC * v.x; m.y = SC * v.y; m.z = SC * v.z; m.w = SC * v.w;
    }
#pragma unroll 8
    for (int t = 1; t < Lc; ++t) {
        v = xp[(size_t)t * (Cn / 4)];
        m.x = fmaf(OMS, m.x, SC * v.x);
        m.y = fmaf(OMS, m.y, SC * v.y);
        m.z = fmaf(OMS, m.z, SC * v.z);
        m.w = fmaf(OMS, m.w, SC * v.w);
    }
    ((float4*)endv)[(size_t)(b * NC + chunk) * (Cn / 4) + cg] = m;
}

__device__ __forceinline__ float pcen_elem(float x, float m, float al, float dl,
                                           float oor, float t3) {
    float lg   = log2f(FLOORV + m);
    float inv1 = exp2f(-al * lg);               // 1 / (FLOOR+m)^alpha
    float base = fmaf(x, inv1, dl);             // x/term1 + delta  (>0)
    return exp2f(oor * log2f(base)) - t3;
}

__global__ __launch_bounds__(256) void k_final(const float* __restrict__ x,
                                               const float* __restrict__ alpha,
                                               const float* __restrict__ delta,
                                               const float* __restrict__ root,
                                               const float* __restrict__ endv,
                                               float* __restrict__ out) {
    int gid   = blockIdx.x * 256 + threadIdx.x;
    int cg    = gid & 31;
    int chunk = (gid >> 5) & (NC - 1);
    int b     = gid >> 12;

    // ---- incoming prefix: m_end_{chunk-1} = sum_{j<chunk} ACH^(chunk-1-j) e_j
    // endv is 4 MiB, L2-hot. Weights below ACH^KWIN (~5e-12) are dropped.
    const float4* ep = (const float4*)endv + (size_t)b * NC * (Cn / 4) + cg;
    float4 acc = {0.f, 0.f, 0.f, 0.f};
    int jstart = chunk - KWIN; if (jstart < 0) jstart = 0;
    for (int j = jstart; j < chunk; ++j) {
        float4 e = ep[(size_t)j * (Cn / 4)];
        acc.x = fmaf(ACH, acc.x, e.x);
        acc.y = fmaf(ACH, acc.y, e.y);
        acc.z = fmaf(ACH, acc.z, e.z);
        acc.w = fmaf(ACH, acc.w, e.w);
    }

    // ---- per-channel params
    int c0 = cg * 4;
    float4 al = *(const float4*)(alpha + c0);
    float4 dl = *(const float4*)(delta + c0);
    float4 rt = *(const float4*)(root + c0);
    al.x = fminf(al.x, 1.f); al.y = fminf(al.y, 1.f); al.z = fminf(al.z, 1.f); al.w = fminf(al.w, 1.f);
    rt.x = fmaxf(rt.x, 1.f); rt.y = fmaxf(rt.y, 1.f); rt.z = fmaxf(rt.z, 1.f); rt.w = fmaxf(rt.w, 1.f);
    float4 oor = {1.f / rt.x, 1.f / rt.y, 1.f / rt.z, 1.f / rt.w};
    float4 t3  = {exp2f(oor.x * log2f(dl.x)), exp2f(oor.y * log2f(dl.y)),
                  exp2f(oor.z * log2f(dl.z)), exp2f(oor.w * log2f(dl.w))};

    // ---- fused EMA + PCEN over the chunk
    size_t xoff = (size_t)(b * Tn + chunk * Lc) * (Cn / 4) + cg;
    const float4* xp = (const float4*)x + xoff;
    float4*       op = (float4*)out + xoff;

    // t = 0 peeled (chunk 0: m = x_0; others: m = OMS*prefix + SC*x_0)
    float4 v = xp[0];
    float4 m;
    if (chunk == 0) {
        m = v;
    } else {
        m.x = fmaf(OMS, acc.x, SC * v.x);
        m.y = fmaf(OMS, acc.y, SC * v.y);
        m.z = fmaf(OMS, acc.z, SC * v.z);
        m.w = fmaf(OMS, acc.w, SC * v.w);
    }
    float4 o;
    o.x = pcen_elem(v.x, m.x, al.x, dl.x, oor.x, t3.x);
    o.y = pcen_elem(v.y, m.y, al.y, dl.y, oor.y, t3.y);
    o.z = pcen_elem(v.z, m.z, al.z, dl.z, oor.z, t3.z);
    o.w = pcen_elem(v.w, m.w, al.w, dl.w, oor.w, t3.w);
    op[0] = o;

#pragma unroll 8
    for (int t = 1; t < Lc; ++t) {
        v = xp[(size_t)t * (Cn / 4)];
        m.x = fmaf(OMS, m.x, SC * v.x);
        m.y = fmaf(OMS, m.y, SC * v.y);
        m.z = fmaf(OMS, m.z, SC * v.z);
        m.w = fmaf(OMS, m.w, SC * v.w);
        o.x = pcen_elem(v.x, m.x, al.x, dl.x, oor.x, t3.x);
        o.y = pcen_elem(v.y, m.y, al.y, dl.y, oor.y, t3.y);
        o.z = pcen_elem(v.z, m.z, al.z, dl.z, oor.z, t3.z);
        o.w = pcen_elem(v.w, m.w, al.w, dl.w, oor.w, t3.w);
        op[(size_t)t * (Cn / 4)] = o;
    }
}

extern "C" void kernel_launch(void* const* d_in, const int* in_sizes, int n_in,
                              void* d_out, int out_size, void* d_ws, size_t ws_size,
                              hipStream_t stream) {
    const float* x     = (const float*)d_in[0];
    const float* alpha = (const float*)d_in[1];
    const float* delta = (const float*)d_in[2];
    const float* root  = (const float*)d_in[3];
    float* out = (float*)d_out;
    float* ws  = (float*)d_ws;   // needs B*NC*C*4 = 4 MiB

    const int total = Bn * NC * (Cn / 4);        // 262144 threads, 1024 blocks
    k_partial<<<total / 256, 256, 0, stream>>>(x, ws);
    k_final<<<total / 256, 256, 0, stream>>>(x, alpha, delta, root, ws, out);
}

// Round 6
// 260.714 us; speedup vs baseline: 1.6730x; 1.0541x over previous
//
#include <hip/hip_runtime.h>

// PCEN: out = (x/(FLOOR+m)^alpha + delta)^(1/root) - delta^(1/root)
// m = EMA over T with s=0.025, m_0 = x_0.
// Shapes: x [B=64, T=4096, C=128] f32, alpha/delta/root [C] f32.
//
// Cost model (R0/R2/R4 consistent): timed window = ~160 us fixed poison fills
// + our kernels + gaps. Optimize our ~95-110 us toward the ~55 us floor.
//
// Two regular (graph-capturable) kernels:
//  k_partial: per-(b,chunk,cg) chunk-local EMA end value -> endv (8 MiB ws)
//  k_final:   per-thread incoming prefix from endv (L2-hot, truncated to the
//             last KWIN=32 sub-chunks = 512 steps; 0.975^512 ~ 2.4e-6),
//             then fused EMA+PCEN.
// R5->R6: compile fixes only.
//  - __builtin_amdgcn_logf/exp2f (bare v_log_f32/v_exp_f32) instead of
//    __log2f/__exp2f which collide with glibc math.h internal macros.
//  - nontemporal stores via ext_vector_type(4) alias (builtin rejects the
//    HIP_vector_type class).

constexpr int Bn = 64, Tn = 4096, Cn = 128;
constexpr int NC = 256;           // chunks along T
constexpr int Lc = Tn / NC;       // 16 timesteps per chunk
constexpr int KWIN = 32;          // prefix window: 32*16 = 512 steps of history
constexpr float SC  = 0.025f;
constexpr float OMS = 1.0f - SC;  // 0.975
constexpr float FLOORV = 1e-6f;

typedef float v4f __attribute__((ext_vector_type(4)));

// (1-s)^Lc, compile-time
__host__ __device__ constexpr float chunk_decay() {
    float a = 1.0f;
    for (int i = 0; i < Lc; ++i) a *= OMS;
    return a;
}
constexpr float ACH = chunk_decay();   // 0.975^16 ~ 0.6672

// Thread mapping: gid = b*(NC*32) + chunk*32 + cg  (cg = float4 group of channels)
// Consecutive lanes -> consecutive channels -> coalesced float4 accesses
// (each half-wave reads a contiguous 512B segment).

__global__ __launch_bounds__(256) void k_partial(const float* __restrict__ x,
                                                 float* __restrict__ endv) {
    int gid   = blockIdx.x * 256 + threadIdx.x;
    int cg    = gid & 31;
    int chunk = (gid >> 5) & (NC - 1);
    int b     = gid >> 13;

    const float4* xp = (const float4*)x + (size_t)(b * Tn + chunk * Lc) * (Cn / 4) + cg;

    // t = 0 peeled: chunk 0 starts with m = x_0 (a_0 = 0); others zero-init.
    float4 v = xp[0];
    float4 m;
    if (chunk == 0) {
        m = v;
    } else {
        m.x = SC * v.x; m.y = SC * v.y; m.z = SC * v.z; m.w = SC * v.w;
    }
#pragma unroll
    for (int t = 1; t < Lc; ++t) {
        v = xp[(size_t)t * (Cn / 4)];
        m.x = fmaf(OMS, m.x, SC * v.x);
        m.y = fmaf(OMS, m.y, SC * v.y);
        m.z = fmaf(OMS, m.z, SC * v.z);
        m.w = fmaf(OMS, m.w, SC * v.w);
    }
    ((float4*)endv)[(size_t)(b * NC + chunk) * (Cn / 4) + cg] = m;
}

__device__ __forceinline__ float pcen_elem(float x, float m, float al, float dl,
                                           float oor, float t3) {
    float lg   = __builtin_amdgcn_logf(FLOORV + m);   // v_log_f32: log2
    float inv1 = __builtin_amdgcn_exp2f(-al * lg);    // 1 / (FLOOR+m)^alpha
    float base = fmaf(x, inv1, dl);                   // x/term1 + delta  (>0)
    return __builtin_amdgcn_exp2f(oor * __builtin_amdgcn_logf(base)) - t3;
}

__global__ __launch_bounds__(256) void k_final(const float* __restrict__ x,
                                               const float* __restrict__ alpha,
                                               const float* __restrict__ delta,
                                               const float* __restrict__ root,
                                               const float* __restrict__ endv,
                                               float* __restrict__ out) {
    int gid   = blockIdx.x * 256 + threadIdx.x;
    int cg    = gid & 31;
    int chunk = (gid >> 5) & (NC - 1);
    int b     = gid >> 13;

    // ---- incoming prefix: m_end_{chunk-1} = sum_{j<chunk} ACH^(chunk-1-j) e_j
    // endv is 8 MiB, L2-hot. Weights below ACH^KWIN (~2.4e-6) are dropped.
    const float4* ep = (const float4*)endv + (size_t)b * NC * (Cn / 4) + cg;
    float4 acc = {0.f, 0.f, 0.f, 0.f};
    if (chunk >= KWIN) {
        const float4* eb = ep + (size_t)(chunk - KWIN) * (Cn / 4);
#pragma unroll
        for (int j = 0; j < KWIN; ++j) {
            float4 e = eb[(size_t)j * (Cn / 4)];
            acc.x = fmaf(ACH, acc.x, e.x);
            acc.y = fmaf(ACH, acc.y, e.y);
            acc.z = fmaf(ACH, acc.z, e.z);
            acc.w = fmaf(ACH, acc.w, e.w);
        }
    } else {
#pragma unroll 8
        for (int j = 0; j < chunk; ++j) {
            float4 e = ep[(size_t)j * (Cn / 4)];
            acc.x = fmaf(ACH, acc.x, e.x);
            acc.y = fmaf(ACH, acc.y, e.y);
            acc.z = fmaf(ACH, acc.z, e.z);
            acc.w = fmaf(ACH, acc.w, e.w);
        }
    }

    // ---- per-channel params (precise one-time transcendentals)
    int c0 = cg * 4;
    float4 al = *(const float4*)(alpha + c0);
    float4 dl = *(const float4*)(delta + c0);
    float4 rt = *(const float4*)(root + c0);
    al.x = fminf(al.x, 1.f); al.y = fminf(al.y, 1.f); al.z = fminf(al.z, 1.f); al.w = fminf(al.w, 1.f);
    rt.x = fmaxf(rt.x, 1.f); rt.y = fmaxf(rt.y, 1.f); rt.z = fmaxf(rt.z, 1.f); rt.w = fmaxf(rt.w, 1.f);
    float4 oor = {1.f / rt.x, 1.f / rt.y, 1.f / rt.z, 1.f / rt.w};
    float4 t3  = {exp2f(oor.x * log2f(dl.x)), exp2f(oor.y * log2f(dl.y)),
                  exp2f(oor.z * log2f(dl.z)), exp2f(oor.w * log2f(dl.w))};

    // ---- fused EMA + PCEN over the chunk
    size_t xoff = (size_t)(b * Tn + chunk * Lc) * (Cn / 4) + cg;
    const float4* xp = (const float4*)x + xoff;
    v4f*          op = (v4f*)out + xoff;

    // t = 0 peeled (chunk 0: m = x_0; others: m = OMS*prefix + SC*x_0)
    float4 v = xp[0];
    float4 m;
    if (chunk == 0) {
        m = v;
    } else {
        m.x = fmaf(OMS, acc.x, SC * v.x);
        m.y = fmaf(OMS, acc.y, SC * v.y);
        m.z = fmaf(OMS, acc.z, SC * v.z);
        m.w = fmaf(OMS, acc.w, SC * v.w);
    }
    v4f o;
    o.x = pcen_elem(v.x, m.x, al.x, dl.x, oor.x, t3.x);
    o.y = pcen_elem(v.y, m.y, al.y, dl.y, oor.y, t3.y);
    o.z = pcen_elem(v.z, m.z, al.z, dl.z, oor.z, t3.z);
    o.w = pcen_elem(v.w, m.w, al.w, dl.w, oor.w, t3.w);
    __builtin_nontemporal_store(o, op);

#pragma unroll
    for (int t = 1; t < Lc; ++t) {
        v = xp[(size_t)t * (Cn / 4)];
        m.x = fmaf(OMS, m.x, SC * v.x);
        m.y = fmaf(OMS, m.y, SC * v.y);
        m.z = fmaf(OMS, m.z, SC * v.z);
        m.w = fmaf(OMS, m.w, SC * v.w);
        o.x = pcen_elem(v.x, m.x, al.x, dl.x, oor.x, t3.x);
        o.y = pcen_elem(v.y, m.y, al.y, dl.y, oor.y, t3.y);
        o.z = pcen_elem(v.z, m.z, al.z, dl.z, oor.z, t3.z);
        o.w = pcen_elem(v.w, m.w, al.w, dl.w, oor.w, t3.w);
        __builtin_nontemporal_store(o, op + (size_t)t * (Cn / 4));
    }
}

extern "C" void kernel_launch(void* const* d_in, const int* in_sizes, int n_in,
                              void* d_out, int out_size, void* d_ws, size_t ws_size,
                              hipStream_t stream) {
    const float* x     = (const float*)d_in[0];
    const float* alpha = (const float*)d_in[1];
    const float* delta = (const float*)d_in[2];
    const float* root  = (const float*)d_in[3];
    float* out = (float*)d_out;
    float* ws  = (float*)d_ws;   // needs B*NC*C*4 = 8 MiB

    const int total = Bn * NC * (Cn / 4);        // 524288 threads, 2048 blocks
    k_partial<<<total / 256, 256, 0, stream>>>(x, ws);
    k_final<<<total / 256, 256, 0, stream>>>(x, alpha, delta, root, ws, out);
}

// Round 7
// 256.131 us; speedup vs baseline: 1.7030x; 1.0179x over previous
//
#include <hip/hip_runtime.h>

// PCEN: out = (x/(FLOOR+m)^alpha + delta)^(1/root) - delta^(1/root)
// m = EMA over T with s=0.025, m_0 = x_0.
// Shapes: x [B=64, T=4096, C=128] f32, alpha/delta/root [C] f32.
//
// Cost model (R0/R2/R4/R6 consistent): timed window = ~161 us poison fills
// + ~25 us launch/gap overhead + our kernels (~75 us in R6).
//
// Two regular (graph-capturable) kernels:
//  k_partial: per-(b,chunk,cg) chunk-local EMA end value -> endv (8 MiB ws);
//             PLUS per-block LDS reduce of its 8 chunk-ends into a
//             super-chunk (128-step) end value -> supv (1 MiB ws).
//  k_final:   per-thread incoming prefix from <=7 sub-ends + 4 super-ends
//             (L2-hot; ACHS^4 ~ 2.4e-6 truncation), then fused EMA+PCEN.
// R6->R7: hierarchical prefix (32 -> ~7.5 loads/thread; 256 -> ~60 MiB L2).

constexpr int Bn = 64, Tn = 4096, Cn = 128;
constexpr int NC = 256;           // chunks along T
constexpr int Lc = Tn / NC;       // 16 timesteps per chunk
constexpr int SUPER = 8;          // chunks per super-chunk (= chunks per block)
constexpr int NSUP = NC / SUPER;  // 32 super-chunks per b
constexpr int SWIN = 4;           // super-prefix window (0.975^512 ~ 2.4e-6)
constexpr float SC  = 0.025f;
constexpr float OMS = 1.0f - SC;  // 0.975
constexpr float FLOORV = 1e-6f;

typedef float v4f __attribute__((ext_vector_type(4)));

__host__ __device__ constexpr float powN(float a, int n) {
    float r = 1.0f;
    for (int i = 0; i < n; ++i) r *= a;
    return r;
}
constexpr float ACH  = powN(OMS, Lc);          // 0.975^16  ~ 0.6672
constexpr float ACHS = powN(OMS, Lc * SUPER);  // 0.975^128 ~ 0.03919

// Thread mapping: gid = b*(NC*32) + chunk*32 + cg  (cg = float4 group of channels)
// Consecutive lanes -> consecutive channels -> coalesced float4 accesses.
// A 256-thread block covers 8 consecutive chunks x 32 cg -> exactly one
// super-chunk per block (chunk0 = (blockIdx&31)*8, b = blockIdx>>5).

__global__ __launch_bounds__(256) void k_partial(const float* __restrict__ x,
                                                 float* __restrict__ endv,
                                                 float* __restrict__ supv) {
    int gid   = blockIdx.x * 256 + threadIdx.x;
    int cg    = gid & 31;
    int chunk = (gid >> 5) & (NC - 1);
    int b     = gid >> 13;
    int sub   = threadIdx.x >> 5;          // chunk index within the block (0..7)

    const float4* xp = (const float4*)x + (size_t)(b * Tn + chunk * Lc) * (Cn / 4) + cg;

    // t = 0 peeled: chunk 0 starts with m = x_0 (a_0 = 0); others zero-init.
    float4 v = xp[0];
    float4 m;
    if (chunk == 0) {
        m = v;
    } else {
        m.x = SC * v.x; m.y = SC * v.y; m.z = SC * v.z; m.w = SC * v.w;
    }
#pragma unroll
    for (int t = 1; t < Lc; ++t) {
        v = xp[(size_t)t * (Cn / 4)];
        m.x = fmaf(OMS, m.x, SC * v.x);
        m.y = fmaf(OMS, m.y, SC * v.y);
        m.z = fmaf(OMS, m.z, SC * v.z);
        m.w = fmaf(OMS, m.w, SC * v.w);
    }
    ((float4*)endv)[(size_t)(b * NC + chunk) * (Cn / 4) + cg] = m;

    // ---- block-level: combine the 8 chunk-ends into the super-chunk end.
    // m_super = fold over chunks: acc = ACH*acc + e_i  (zero init).
    __shared__ float4 lds[SUPER][32];
    lds[sub][cg] = m;
    __syncthreads();
    if (threadIdx.x < 32) {                 // one thread per cg
        float4 acc = lds[0][threadIdx.x];
#pragma unroll
        for (int i = 1; i < SUPER; ++i) {
            float4 e = lds[i][threadIdx.x];
            acc.x = fmaf(ACH, acc.x, e.x);
            acc.y = fmaf(ACH, acc.y, e.y);
            acc.z = fmaf(ACH, acc.z, e.z);
            acc.w = fmaf(ACH, acc.w, e.w);
        }
        // supv float4 index = (b*NSUP + sc)*32 + cg = blockIdx.x*32 + cg
        ((float4*)supv)[(size_t)blockIdx.x * 32 + threadIdx.x] = acc;
    }
}

__device__ __forceinline__ float pcen_elem(float x, float m, float al, float dl,
                                           float oor, float t3) {
    float lg   = __builtin_amdgcn_logf(FLOORV + m);   // v_log_f32: log2
    float inv1 = __builtin_amdgcn_exp2f(-al * lg);    // 1 / (FLOOR+m)^alpha
    float base = fmaf(x, inv1, dl);                   // x/term1 + delta  (>0)
    return __builtin_amdgcn_exp2f(oor * __builtin_amdgcn_logf(base)) - t3;
}

__global__ __launch_bounds__(256) void k_final(const float* __restrict__ x,
                                               const float* __restrict__ alpha,
                                               const float* __restrict__ delta,
                                               const float* __restrict__ root,
                                               const float* __restrict__ endv,
                                               const float* __restrict__ supv,
                                               float* __restrict__ out) {
    int gid   = blockIdx.x * 256 + threadIdx.x;
    int cg    = gid & 31;
    int chunk = (gid >> 5) & (NC - 1);
    int b     = gid >> 13;

    // ---- incoming prefix m_end_{chunk-1}:
    //   super part: fold E_s over s in [max(0,sc-SWIN), sc)   (ACHS weights)
    //   sub part:   fold e_j over j in [sc*SUPER, chunk)      (ACH weights)
    int sc = chunk >> 3;
    const float4* Ep = (const float4*)supv + (size_t)b * NSUP * 32 + cg;
    const float4* ep = (const float4*)endv + (size_t)b * NC * (Cn / 4) + cg;

    float4 acc = {0.f, 0.f, 0.f, 0.f};
    int s0 = sc - SWIN; if (s0 < 0) s0 = 0;
#pragma unroll 4
    for (int s = s0; s < sc; ++s) {
        float4 E = Ep[(size_t)s * 32];
        acc.x = fmaf(ACHS, acc.x, E.x);
        acc.y = fmaf(ACHS, acc.y, E.y);
        acc.z = fmaf(ACHS, acc.z, E.z);
        acc.w = fmaf(ACHS, acc.w, E.w);
    }
#pragma unroll 7
    for (int j = sc * SUPER; j < chunk; ++j) {
        float4 e = ep[(size_t)j * (Cn / 4)];
        acc.x = fmaf(ACH, acc.x, e.x);
        acc.y = fmaf(ACH, acc.y, e.y);
        acc.z = fmaf(ACH, acc.z, e.z);
        acc.w = fmaf(ACH, acc.w, e.w);
    }

    // ---- per-channel params (precise one-time transcendentals)
    int c0 = cg * 4;
    float4 al = *(const float4*)(alpha + c0);
    float4 dl = *(const float4*)(delta + c0);
    float4 rt = *(const float4*)(root + c0);
    al.x = fminf(al.x, 1.f); al.y = fminf(al.y, 1.f); al.z = fminf(al.z, 1.f); al.w = fminf(al.w, 1.f);
    rt.x = fmaxf(rt.x, 1.f); rt.y = fmaxf(rt.y, 1.f); rt.z = fmaxf(rt.z, 1.f); rt.w = fmaxf(rt.w, 1.f);
    float4 oor = {1.f / rt.x, 1.f / rt.y, 1.f / rt.z, 1.f / rt.w};
    float4 t3  = {exp2f(oor.x * log2f(dl.x)), exp2f(oor.y * log2f(dl.y)),
                  exp2f(oor.z * log2f(dl.z)), exp2f(oor.w * log2f(dl.w))};

    // ---- fused EMA + PCEN over the chunk
    size_t xoff = (size_t)(b * Tn + chunk * Lc) * (Cn / 4) + cg;
    const float4* xp = (const float4*)x + xoff;
    v4f*          op = (v4f*)out + xoff;

    // t = 0 peeled (chunk 0: m = x_0; others: m = OMS*prefix + SC*x_0)
    float4 v = xp[0];
    float4 m;
    if (chunk == 0) {
        m = v;
    } else {
        m.x = fmaf(OMS, acc.x, SC * v.x);
        m.y = fmaf(OMS, acc.y, SC * v.y);
        m.z = fmaf(OMS, acc.z, SC * v.z);
        m.w = fmaf(OMS, acc.w, SC * v.w);
    }
    v4f o;
    o.x = pcen_elem(v.x, m.x, al.x, dl.x, oor.x, t3.x);
    o.y = pcen_elem(v.y, m.y, al.y, dl.y, oor.y, t3.y);
    o.z = pcen_elem(v.z, m.z, al.z, dl.z, oor.z, t3.z);
    o.w = pcen_elem(v.w, m.w, al.w, dl.w, oor.w, t3.w);
    __builtin_nontemporal_store(o, op);

#pragma unroll
    for (int t = 1; t < Lc; ++t) {
        v = xp[(size_t)t * (Cn / 4)];
        m.x = fmaf(OMS, m.x, SC * v.x);
        m.y = fmaf(OMS, m.y, SC * v.y);
        m.z = fmaf(OMS, m.z, SC * v.z);
        m.w = fmaf(OMS, m.w, SC * v.w);
        o.x = pcen_elem(v.x, m.x, al.x, dl.x, oor.x, t3.x);
        o.y = pcen_elem(v.y, m.y, al.y, dl.y, oor.y, t3.y);
        o.z = pcen_elem(v.z, m.z, al.z, dl.z, oor.z, t3.z);
        o.w = pcen_elem(v.w, m.w, al.w, dl.w, oor.w, t3.w);
        __builtin_nontemporal_store(o, op + (size_t)t * (Cn / 4));
    }
}

extern "C" void kernel_launch(void* const* d_in, const int* in_sizes, int n_in,
                              void* d_out, int out_size, void* d_ws, size_t ws_size,
                              hipStream_t stream) {
    const float* x     = (const float*)d_in[0];
    const float* alpha = (const float*)d_in[1];
    const float* delta = (const float*)d_in[2];
    const float* root  = (const float*)d_in[3];
    float* out  = (float*)d_out;
    float* endv = (float*)d_ws;                       // 8 MiB
    float* supv = (float*)d_ws + (size_t)Bn * NC * Cn; // +1 MiB (ws needs 9 MiB)

    const int total = Bn * NC * (Cn / 4);        // 524288 threads, 2048 blocks
    k_partial<<<total / 256, 256, 0, stream>>>(x, endv, supv);
    k_final<<<total / 256, 256, 0, stream>>>(x, alpha, delta, root, endv, supv, out);
}